// Round 7
// baseline (10.620 us; speedup 1.0000x reference)
//
#include <hip/hip_runtime.h>

#define NB 8
#define SS 43
#define NQ 13
#define DD 608
#define KK 4
#define NF4 (DD / 4)   // 152 float4 per x-row

__global__ __launch_bounds__(256) void imp_enc_kernel(
    const float* __restrict__ x, const float* __restrict__ scores,
    const float* __restrict__ Wff, const float* __restrict__ bff,
    float* __restrict__ out)
{
    const int bi   = blockIdx.x;            // 0 .. B*NQ-1
    const int b    = bi / NQ;
    const int i    = bi % NQ;
    const int k    = threadIdx.x >> 6;      // wave id 0..3 = which gather this wave owns
    const int lane = threadIdx.x & 63;

    const float4* W4  = (const float4*)Wff;   // row e: W_top = W4[e], W_bot = W4[DD+e]
    const float4* xs4 = (const float4*)(x + ((size_t)b * SS + i) * DD);

    // early independent loads
    float4 bias = *(const float4*)bff;
    const float* srow = scores + ((size_t)b * SS + i) * SS;
    float myv = (lane < NQ) ? srow[lane] : -INFINITY;   // coalesced, lane j holds score j

    // ---- self-row dot W_top (independent of top-k; hides score-load latency) ----
    float acc[4] = {0.f, 0.f, 0.f, 0.f};
    #pragma unroll
    for (int it = 0; it < 3; ++it) {
        const int f = lane + it * 64;
        if (f < NF4) {
            float4 xv = xs4[f];
            const float xe[4] = {xv.x, xv.y, xv.z, xv.w};
            #pragma unroll
            for (int u = 0; u < 4; ++u) {
                float4 wt = W4[f * 4 + u];
                acc[0] += xe[u] * wt.x;
                acc[1] += xe[u] * wt.y;
                acc[2] += xe[u] * wt.z;
                acc[3] += xe[u] * wt.w;
            }
        }
    }

    // ---- lane-parallel top-4 (each wave computes it redundantly; no barrier) ----
    // rank = #elements strictly better; ties -> lower index (matches lax.top_k)
    int rank = 0;
    #pragma unroll
    for (int m = 0; m < NQ; ++m) {
        float vm = __shfl(myv, m, 64);
        if (vm > myv || (vm == myv && m < lane)) ++rank;
    }
    int idx[KK];
    #pragma unroll
    for (int kk = 0; kk < KK; ++kk) {
        unsigned long long msk = __ballot(lane < NQ && rank == kk);
        idx[kk] = (int)__ffsll(msk) - 1;   // wave-uniform
    }

    // ---- this wave's gathered row dot W_bot, accumulated into the same acc ----
    const float4* xg4 = (const float4*)(x + ((size_t)b * SS + idx[k]) * DD);
    #pragma unroll
    for (int it = 0; it < 3; ++it) {
        const int f = lane + it * 64;
        if (f < NF4) {
            float4 gv = xg4[f];
            const float ge[4] = {gv.x, gv.y, gv.z, gv.w};
            #pragma unroll
            for (int u = 0; u < 4; ++u) {
                float4 wb = W4[DD + f * 4 + u];
                acc[0] += ge[u] * wb.x;
                acc[1] += ge[u] * wb.y;
                acc[2] += ge[u] * wb.z;
                acc[3] += ge[u] * wb.w;
            }
        }
    }

    // ---- butterfly reduce 4 values across the wave (self+gather pre-merged) ----
    #pragma unroll
    for (int off = 32; off > 0; off >>= 1) {
        #pragma unroll
        for (int c = 0; c < 4; ++c) acc[c] += __shfl_xor(acc[c], off, 64);
    }

    // ---- write: wave k owns row j=idx[k]; wave 0 also writes base rows ----
    if (lane < NQ * 4) {
        const int j = lane >> 2;
        const int c = lane & 3;
        // explicit select chains (no runtime register-array indexing, rule #20)
        const float vA = (c & 2) ? ((c & 1) ? acc[3] : acc[2])
                                 : ((c & 1) ? acc[1] : acc[0]);
        const float bc = (c & 2) ? ((c & 1) ? bias.w : bias.z)
                                 : ((c & 1) ? bias.y : bias.x);
        const bool sel = (j == idx[0]) | (j == idx[1]) | (j == idx[2]) | (j == idx[3]);
        float* orow = out + (size_t)bi * (NQ * 4);
        if (j == idx[k]) {
            orow[lane] = vA + bc;                   // this wave's selected row
        } else if (k == 0 && !sel) {
            orow[lane] = (c == 0) ? 1.0f : 0.0f;    // base rows, disjoint addresses
        }
    }
}

extern "C" void kernel_launch(void* const* d_in, const int* in_sizes, int n_in,
                              void* d_out, int out_size, void* d_ws, size_t ws_size,
                              hipStream_t stream) {
    const float* x      = (const float*)d_in[0];
    const float* scores = (const float*)d_in[1];
    const float* Wff    = (const float*)d_in[2];
    const float* bff    = (const float*)d_in[3];
    float* out = (float*)d_out;

    imp_enc_kernel<<<NB * NQ, 256, 0, stream>>>(x, scores, Wff, bff, out);
}

// Round 8
// 9.342 us; speedup vs baseline: 1.1368x; 1.1368x over previous
//
#include <hip/hip_runtime.h>

#define NB 8
#define SS 43
#define NQ 13
#define DD 608
#define KK 4
#define NF4 (DD / 4)   // 152 float4 per x-row

// Final kernel (R3 structure, best measured: 9.38 us).
// Measured time is ~9 us fixed graph-replay/launch overhead + <1 us GPU work;
// all kernel-side variants (R4-R7) land within the +-0.6-1 us noise band.
__global__ __launch_bounds__(256) void imp_enc_kernel(
    const float* __restrict__ x, const float* __restrict__ scores,
    const float* __restrict__ Wff, const float* __restrict__ bff,
    float* __restrict__ out)
{
    const int bi   = blockIdx.x;            // 0 .. B*NQ-1
    const int b    = bi / NQ;
    const int i    = bi % NQ;
    const int k    = threadIdx.x >> 6;      // wave id 0..3 = which gather this wave owns
    const int lane = threadIdx.x & 63;

    const float4* W4  = (const float4*)Wff;     // W4[e] = row e (4 cols); W_bot row e = W4[DD+e]
    const float4* xs4 = (const float4*)(x + ((size_t)b * SS + i) * DD);

    // early independent loads
    float4 bias = *(const float4*)bff;
    const float* srow = scores + ((size_t)b * SS + i) * SS;
    float myv = (lane < NQ) ? srow[lane] : -INFINITY;   // coalesced, lane j holds score j

    // ---- self-row dot W_top (independent of top-k; hides score-load latency) ----
    float accS[4] = {0.f, 0.f, 0.f, 0.f};
    #pragma unroll
    for (int it = 0; it < 3; ++it) {
        const int f = lane + it * 64;
        if (f < NF4) {
            float4 xv = xs4[f];
            const float xe[4] = {xv.x, xv.y, xv.z, xv.w};
            #pragma unroll
            for (int u = 0; u < 4; ++u) {
                float4 wt = W4[f * 4 + u];
                accS[0] += xe[u] * wt.x;
                accS[1] += xe[u] * wt.y;
                accS[2] += xe[u] * wt.z;
                accS[3] += xe[u] * wt.w;
            }
        }
    }

    // ---- lane-parallel top-4 (each wave computes it redundantly; no barrier) ----
    // rank = #elements strictly better; ties -> lower index (matches lax.top_k)
    int rank = 0;
    #pragma unroll
    for (int m = 0; m < NQ; ++m) {
        float vm = __shfl(myv, m, 64);
        if (vm > myv || (vm == myv && m < lane)) ++rank;
    }
    int idx[KK];
    #pragma unroll
    for (int kk = 0; kk < KK; ++kk) {
        unsigned long long msk = __ballot(lane < NQ && rank == kk);
        idx[kk] = (int)__ffsll(msk) - 1;   // wave-uniform
    }

    // ---- this wave's gathered row dot W_bot ----
    const float4* xg4 = (const float4*)(x + ((size_t)b * SS + idx[k]) * DD);
    float accG[4] = {0.f, 0.f, 0.f, 0.f};
    #pragma unroll
    for (int it = 0; it < 3; ++it) {
        const int f = lane + it * 64;
        if (f < NF4) {
            float4 gv = xg4[f];
            const float ge[4] = {gv.x, gv.y, gv.z, gv.w};
            #pragma unroll
            for (int u = 0; u < 4; ++u) {
                float4 wb = W4[DD + f * 4 + u];
                accG[0] += ge[u] * wb.x;
                accG[1] += ge[u] * wb.y;
                accG[2] += ge[u] * wb.z;
                accG[3] += ge[u] * wb.w;
            }
        }
    }

    // ---- butterfly reduce 8 values across the wave ----
    #pragma unroll
    for (int off = 32; off > 0; off >>= 1) {
        #pragma unroll
        for (int c = 0; c < 4; ++c) {
            accS[c] += __shfl_xor(accS[c], off, 64);
            accG[c] += __shfl_xor(accG[c], off, 64);
        }
    }

    // ---- write: wave k owns row j=idx[k]; wave 0 also writes base rows ----
    if (lane < NQ * 4) {
        const int j = lane >> 2;
        const int c = lane & 3;
        // explicit select chains (no runtime register-array indexing, rule #20)
        const float vS = (c & 2) ? ((c & 1) ? accS[3] : accS[2])
                                 : ((c & 1) ? accS[1] : accS[0]);
        const float vG = (c & 2) ? ((c & 1) ? accG[3] : accG[2])
                                 : ((c & 1) ? accG[1] : accG[0]);
        const float bc = (c & 2) ? ((c & 1) ? bias.w : bias.z)
                                 : ((c & 1) ? bias.y : bias.x);
        const bool sel = (j == idx[0]) | (j == idx[1]) | (j == idx[2]) | (j == idx[3]);
        float* orow = out + (size_t)bi * (NQ * 4);
        if (j == idx[k]) {
            orow[lane] = vS + vG + bc;              // this wave's selected row
        } else if (k == 0 && !sel) {
            orow[lane] = (c == 0) ? 1.0f : 0.0f;    // base rows, disjoint addresses
        }
    }
}

extern "C" void kernel_launch(void* const* d_in, const int* in_sizes, int n_in,
                              void* d_out, int out_size, void* d_ws, size_t ws_size,
                              hipStream_t stream) {
    const float* x      = (const float*)d_in[0];
    const float* scores = (const float*)d_in[1];
    const float* Wff    = (const float*)d_in[2];
    const float* bff    = (const float*)d_in[3];
    float* out = (float*)d_out;

    imp_enc_kernel<<<NB * NQ, 256, 0, stream>>>(x, scores, Wff, bff, out);
}